// Round 9
// baseline (221.629 us; speedup 1.0000x reference)
//
#include <hip/hip_runtime.h>
#include <hip/hip_bf16.h>

#define DMODEL 1024
#define NHEADS 16
#define HDIM   64
#define BATCH  2
#define SEQ    2048
#define XELEMS ((size_t)BATCH * SEQ * DMODEL)   // 4,194,304
#define WELEMS ((size_t)DMODEL * DMODEL)        // 1,048,576

typedef __attribute__((ext_vector_type(8))) __bf16 bf16x8;
typedef __attribute__((ext_vector_type(4))) float  f32x4;
typedef __attribute__((ext_vector_type(2))) float  f32x2;
typedef __attribute__((ext_vector_type(4))) unsigned int   u32x4;
typedef __attribute__((ext_vector_type(4))) unsigned short u16x4;
typedef __attribute__((ext_vector_type(8))) unsigned short u16x8;

typedef const __attribute__((address_space(1))) void* gas_t;
typedef __attribute__((address_space(3))) void* las_t;

static __device__ __forceinline__ unsigned short f2bf(float f) {
  return __builtin_bit_cast(unsigned short, __float2bfloat16(f));
}
static __device__ __forceinline__ float bf2f(unsigned short u) {
  return __bfloat162float(__builtin_bit_cast(__hip_bfloat16, u));
}

// ---------------------------------------------------------------------------
// Dtype probe. flags[0]=1 iff float inputs are f32 (else bf16).
// flags[1]=1 iff token_positions is int64 (else int32).
// ---------------------------------------------------------------------------
__global__ __launch_bounds__(64) void probe_kernel(const unsigned int* __restrict__ x,
                                                   const int* __restrict__ pos,
                                                   int* __restrict__ flags) {
  const int lane = threadIdx.x;
  int bad = 0;
#pragma unroll
  for (int i = 0; i < 32; ++i) {
    const unsigned int u = x[lane * 32 + i];
    if (((u >> 23) & 0xFFu) == 0xFFu) bad++;
  }
  int zodd = 0;
#pragma unroll
  for (int i = 0; i < 4; ++i)
    if (pos[lane * 8 + 2 * i + 1] == 0) zodd++;
#pragma unroll
  for (int s = 1; s < 64; s <<= 1) {
    bad  += __shfl_xor(bad, s);
    zodd += __shfl_xor(zodd, s);
  }
  if (lane == 0) {
    flags[0] = (bad < 64) ? 1 : 0;    // 1 => f32 inputs
    flags[1] = (zodd >= 200) ? 1 : 0; // 1 => int64 positions
  }
}

// ---------------------------------------------------------------------------
// RoPE cos/sin table: per (b,s,pair) -> {cos, sin}. 131072 entries (1 MB).
// ---------------------------------------------------------------------------
__global__ __launch_bounds__(256) void rope_table_kernel(const int* __restrict__ pos,
                                                         const int* __restrict__ flags,
                                                         float* __restrict__ tab) {
  const int i = blockIdx.x * 256 + threadIdx.x;   // 0..131071
  const int pd = i & 31, rs = i >> 5;             // rs = b*SEQ + s
  const int pv = flags[1] ? pos[2 * rs] : pos[rs];
  const float ang = (float)pv * exp2f(-(float)pd * 0.41524101186092026f);
  f32x2 t; t[0] = cosf(ang); t[1] = sinf(ang);
  *(f32x2*)&tab[2 * i] = t;
}

// ---------------------------------------------------------------------------
// Canonicalize x,Wq,Wk,Wv,Wo into one contiguous bf16 buffer [x | Wq Wk Wv Wo].
// ---------------------------------------------------------------------------
__global__ __launch_bounds__(256) void conv_kernel(
    const void* __restrict__ x,
    const void* __restrict__ w0, const void* __restrict__ w1,
    const void* __restrict__ w2, const void* __restrict__ w3,
    unsigned short* __restrict__ dst, const int* __restrict__ flags) {
  const size_t e = ((size_t)blockIdx.x * 256 + threadIdx.x) * 8;
  const void* src;
  size_t off;
  if (e < XELEMS) { src = x; off = e; }
  else {
    const size_t r = e - XELEMS;
    const int wi = (int)(r >> 20);
    src = (wi == 0) ? w0 : (wi == 1) ? w1 : (wi == 2) ? w2 : w3;
    off = r & (WELEMS - 1);
  }
  if (flags[0]) {
    const float* s = (const float*)src + off;
    const f32x4 a = *(const f32x4*)(s);
    const f32x4 b = *(const f32x4*)(s + 4);
    u16x8 o8;
#pragma unroll
    for (int j = 0; j < 4; ++j) o8[j] = f2bf(a[j]);
#pragma unroll
    for (int j = 0; j < 4; ++j) o8[4 + j] = f2bf(b[j]);
    *(u16x8*)(dst + e) = o8;
  } else {
    *(u32x4*)(dst + e) = *(const u32x4*)((const unsigned short*)src + off);
  }
}

// ---------------------------------------------------------------------------
// Shared GEMM core (128x128 tile): 2-phase double-buffered LDS.
// ---------------------------------------------------------------------------
__device__ __forceinline__ void gemm_core(const unsigned short* __restrict__ Ag,
                                          const unsigned short* __restrict__ Bg,
                                          unsigned short* As, unsigned short* Bs,
                                          int bm, int bn, f32x4 acc[4][4]) {
  const int tid = threadIdx.x;
  const int lane = tid & 63;
  const int w  = tid >> 6;
  const int wm = w >> 1, wn = w & 1;
  const int c = lane & 15, g = lane >> 4;
  const int r0 = tid >> 2;
  const int s0 = (tid & 3) * 8;

  auto stage = [&](int buf, int k0) {
    unsigned short* ad = As + buf * 4096;
    unsigned short* bd = Bs + buf * 4096;
    __builtin_amdgcn_global_load_lds((gas_t)(Ag + (size_t)(bm + r0) * DMODEL + k0 + s0),
                                     (las_t)(ad + tid * 8), 16, 0, 0);
    __builtin_amdgcn_global_load_lds((gas_t)(Ag + (size_t)(bm + r0 + 64) * DMODEL + k0 + s0),
                                     (las_t)(ad + (tid + 256) * 8), 16, 0, 0);
    __builtin_amdgcn_global_load_lds((gas_t)(Bg + (size_t)(bn + r0) * DMODEL + k0 + s0),
                                     (las_t)(bd + tid * 8), 16, 0, 0);
    __builtin_amdgcn_global_load_lds((gas_t)(Bg + (size_t)(bn + r0 + 64) * DMODEL + k0 + s0),
                                     (las_t)(bd + (tid + 256) * 8), 16, 0, 0);
  };

  stage(0, 0);
  __syncthreads();
  for (int k0 = 0; k0 < DMODEL; k0 += 32) {
    const int cur = (k0 >> 5) & 1;
    if (k0 + 32 < DMODEL) stage(cur ^ 1, k0 + 32);
    const unsigned short* ar = As + cur * 4096;
    const unsigned short* br = Bs + cur * 4096;
    bf16x8 af[4], bfr[4];
#pragma unroll
    for (int m = 0; m < 4; ++m)
      af[m] = *(const bf16x8*)&ar[(wm * 64 + m * 16 + c) * 32 + g * 8];
#pragma unroll
    for (int n = 0; n < 4; ++n)
      bfr[n] = *(const bf16x8*)&br[(wn * 64 + n * 16 + c) * 32 + g * 8];
    __builtin_amdgcn_s_setprio(1);
#pragma unroll
    for (int m = 0; m < 4; ++m)
#pragma unroll
      for (int n = 0; n < 4; ++n)
        acc[m][n] = __builtin_amdgcn_mfma_f32_16x16x32_bf16(af[m], bfr[n], acc[m][n], 0, 0, 0);
    __builtin_amdgcn_s_setprio(0);
    __syncthreads();
  }
}

// ---------------------------------------------------------------------------
// QKV projection. grid = (32, 8, 3). Q,K stored [B,H,S,64]; V stored
// transposed [B,H,64,S].
// ---------------------------------------------------------------------------
__global__ __launch_bounds__(256) void qkv_gemm_kernel(
    const unsigned short* __restrict__ x,
    const unsigned short* __restrict__ Wq, const unsigned short* __restrict__ Wk,
    const unsigned short* __restrict__ Wv,
    unsigned short* __restrict__ qo, unsigned short* __restrict__ ko,
    unsigned short* __restrict__ vto) {
  __shared__ unsigned short As[2 * 128 * 32];
  __shared__ unsigned short Bs[2 * 128 * 32];
  const int z = blockIdx.z;
  const unsigned short* W = (z == 0) ? Wq : (z == 1) ? Wk : Wv;
  const int bm = blockIdx.x * 128, bn = blockIdx.y * 128;
  f32x4 acc[4][4];
#pragma unroll
  for (int m = 0; m < 4; ++m)
#pragma unroll
    for (int n = 0; n < 4; ++n)
#pragma unroll
      for (int j = 0; j < 4; ++j) acc[m][n][j] = 0.f;

  gemm_core(x, W, As, Bs, bm, bn, acc);

  const int tid = threadIdx.x, lane = tid & 63, w = tid >> 6;
  const int wm = w >> 1, wn = w & 1, c = lane & 15, g4 = lane >> 4;
#pragma unroll
  for (int m = 0; m < 4; ++m) {
#pragma unroll
    for (int n = 0; n < 4; ++n) {
      const int col = bn + wn * 64 + n * 16 + c;
      const int h = col >> 6, d = col & 63;
      const int row0 = bm + wm * 64 + m * 16 + g4 * 4;
      if (z == 2) {
        const int b = row0 >> 11, s0 = row0 & (SEQ - 1);
        u16x4 pk;
#pragma unroll
        for (int j = 0; j < 4; ++j) pk[j] = f2bf(acc[m][n][j]);
        *(u16x4*)&vto[((size_t)(b * NHEADS + h) * HDIM + d) * SEQ + s0] = pk;
      } else {
        unsigned short* dst = z ? ko : qo;
#pragma unroll
        for (int j = 0; j < 4; ++j) {
          const int row = row0 + j;
          const int b = row >> 11, s = row & (SEQ - 1);
          dst[((size_t)(b * NHEADS + h) * SEQ + s) * HDIM + d] = f2bf(acc[m][n][j]);
        }
      }
    }
  }
}

// ---------------------------------------------------------------------------
// Output projection, 64x128 tile: out = O[4096x1024] * Wo^T. grid (64,8).
// ---------------------------------------------------------------------------
__global__ __launch_bounds__(256) void out_gemm_kernel(
    const unsigned short* __restrict__ A, const unsigned short* __restrict__ Wo,
    void* __restrict__ outv, const int* __restrict__ flags) {
  __shared__ unsigned short As[2 * 64 * 32];
  __shared__ unsigned short Bs[2 * 128 * 32];
  const int bm = blockIdx.x * 64, bn = blockIdx.y * 128;
  const int tid = threadIdx.x, lane = tid & 63, w = tid >> 6;
  const int c = lane & 15, g = lane >> 4;
  const int r0 = tid >> 2, s0 = (tid & 3) * 8;
  f32x4 acc[4][2];
#pragma unroll
  for (int m = 0; m < 4; ++m)
#pragma unroll
    for (int n = 0; n < 2; ++n)
#pragma unroll
      for (int j = 0; j < 4; ++j) acc[m][n][j] = 0.f;

  auto stage = [&](int buf, int k0) {
    __builtin_amdgcn_global_load_lds((gas_t)(A + (size_t)(bm + r0) * DMODEL + k0 + s0),
                                     (las_t)(As + buf * 2048 + tid * 8), 16, 0, 0);
    __builtin_amdgcn_global_load_lds((gas_t)(Wo + (size_t)(bn + r0) * DMODEL + k0 + s0),
                                     (las_t)(Bs + buf * 4096 + tid * 8), 16, 0, 0);
    __builtin_amdgcn_global_load_lds((gas_t)(Wo + (size_t)(bn + r0 + 64) * DMODEL + k0 + s0),
                                     (las_t)(Bs + buf * 4096 + (tid + 256) * 8), 16, 0, 0);
  };

  stage(0, 0);
  __syncthreads();
  for (int k0 = 0; k0 < DMODEL; k0 += 32) {
    const int cur = (k0 >> 5) & 1;
    if (k0 + 32 < DMODEL) stage(cur ^ 1, k0 + 32);
    const unsigned short* ar = As + cur * 2048;
    const unsigned short* br = Bs + cur * 4096;
    bf16x8 af[4], bfr[2];
#pragma unroll
    for (int m = 0; m < 4; ++m)
      af[m] = *(const bf16x8*)&ar[(m * 16 + c) * 32 + g * 8];
#pragma unroll
    for (int n = 0; n < 2; ++n)
      bfr[n] = *(const bf16x8*)&br[(w * 32 + n * 16 + c) * 32 + g * 8];
    __builtin_amdgcn_s_setprio(1);
#pragma unroll
    for (int m = 0; m < 4; ++m)
#pragma unroll
      for (int n = 0; n < 2; ++n)
        acc[m][n] = __builtin_amdgcn_mfma_f32_16x16x32_bf16(af[m], bfr[n], acc[m][n], 0, 0, 0);
    __builtin_amdgcn_s_setprio(0);
    __syncthreads();
  }

  const int f32o = flags[0];
  if (f32o) {
    float* out = (float*)outv;
#pragma unroll
    for (int m = 0; m < 4; ++m)
#pragma unroll
      for (int n = 0; n < 2; ++n) {
        const int col = bn + w * 32 + n * 16 + c;
#pragma unroll
        for (int j = 0; j < 4; ++j) {
          const int row = bm + m * 16 + g * 4 + j;
          out[(size_t)row * DMODEL + col] = acc[m][n][j];
        }
      }
  } else {
    unsigned short* out = (unsigned short*)outv;
#pragma unroll
    for (int m = 0; m < 4; ++m)
#pragma unroll
      for (int n = 0; n < 2; ++n) {
        const int col = bn + w * 32 + n * 16 + c;
#pragma unroll
        for (int j = 0; j < 4; ++j) {
          const int row = bm + m * 16 + g * 4 + j;
          out[(size_t)row * DMODEL + col] = f2bf(acc[m][n][j]);
        }
      }
  }
}

// ---------------------------------------------------------------------------
// RoPE in-place on Q and K ([B,H,S,64]) via precomputed cos/sin table.
// Q pre-scaled by 0.125.
// ---------------------------------------------------------------------------
__global__ __launch_bounds__(256) void rope_kernel(unsigned short* __restrict__ q,
                                                   unsigned short* __restrict__ k,
                                                   const float* __restrict__ tab) {
  const int idx = blockIdx.x * 256 + threadIdx.x;
  const int tsel = idx >> 21;
  const int p = idx & ((1 << 21) - 1);
  const int j = p & 31;
  const int s = (p >> 5) & (SEQ - 1);
  const int bh = p >> 16;
  const int b = bh >> 4;
  unsigned short* base = tsel ? k : q;
  const float sc = tsel ? 1.0f : 0.125f;
  const f32x2 t = *(const f32x2*)&tab[(((size_t)(b * SEQ + s)) * 32 + j) * 2];
  const float cs = t[0], sn = t[1];
  unsigned int* wp = (unsigned int*)base + ((p >> 5) * 32 + j);
  const unsigned int u = *wp;
  const float e = bf2f((unsigned short)(u & 0xffffu));
  const float o = bf2f((unsigned short)(u >> 16));
  *wp = (unsigned int)f2bf((e * cs - o * sn) * sc) |
        ((unsigned int)f2bf((e * sn + o * cs) * sc) << 16);
}

// ---------------------------------------------------------------------------
// Flash attention v7 — BARRIER-FREE. K and V fragments loaded directly
// global->VGPR (no LDS staging, no __syncthreads anywhere): for mfma(K,Q)
// lane (c,g)'s A-frag is a contiguous 16B at K[(kvb+n*16+c)*64 + kk*32 + g*8];
// same for V^T. Waves are fully independent; V loads issued under softmax.
// Only LDS is the wave-private Ps (XOR-swizzled, lgkm-ordered within wave).
// ---------------------------------------------------------------------------
#define MNEG -1e30f
#define QBLK 64
#define LOG2E 1.4426950408889634f

__global__ __launch_bounds__(256, 4) void flash_kernel(
    const unsigned short* __restrict__ q, const unsigned short* __restrict__ k,
    const unsigned short* __restrict__ vt, unsigned short* __restrict__ o) {
  __shared__ unsigned short Ps[64 * 64];      // 8 KB, XOR-swizzled, wave-private rows

  const int wg = blockIdx.x;                  // 0..1023, sorted big-first
  const int qt = (SEQ / QBLK - 1) - (wg >> 5);
  const int bh = wg & 31;
  const int qbase = qt * QBLK;
  const int tid = threadIdx.x, lane = tid & 63, w = tid >> 6;
  const int c = lane & 15, g = lane >> 4;
  const int wq = w * 16;
  const size_t tb = (size_t)bh * SEQ * HDIM;

  // ---- Q fragments direct to registers (q pre-scaled by 0.125 in rope) ----
  bf16x8 qf[2];
#pragma unroll
  for (int kk = 0; kk < 2; ++kk)
    qf[kk] = *(const bf16x8*)(q + tb + (size_t)(qbase + wq + c) * HDIM + kk * 32 + g * 8);

  // per-lane invariant element offsets into K tile / V^T tile
  // K frag (kk,n): (n*16+c)*HDIM + kk*32 + g*8   (16B aligned)
  // V frag (kk,n): (n*16+c)*SEQ  + kk*32 + g*8   (16B aligned)
  const unsigned short* kbase = k + tb + (size_t)(c)*HDIM + g * 8;
  const unsigned short* vbase = vt + tb + (size_t)(c)*SEQ + g * 8;

  f32x4 acco[4];
#pragma unroll
  for (int n = 0; n < 4; ++n)
#pragma unroll
    for (int j = 0; j < 4; ++j) acco[n][j] = 0.f;
  float m_r = MNEG, l_r = 0.f;

  const int pr = wq + c;
  const int px = (pr & 7) << 3;

  const int nkv = qt + 1;
  for (int kt = 0; kt < nkv; ++kt) {
    const int kvb = kt * 64;

    // ---- K fragments: 8 x 16B direct loads ----
    bf16x8 ak[2][4];
#pragma unroll
    for (int kk = 0; kk < 2; ++kk)
#pragma unroll
      for (int n = 0; n < 4; ++n)
        ak[kk][n] = *(const bf16x8*)(kbase + (size_t)(kvb + n * 16) * HDIM + kk * 32);

    // ---- S^T = K Q^T ----
    f32x4 accs[4];
#pragma unroll
    for (int n = 0; n < 4; ++n)
#pragma unroll
      for (int j = 0; j < 4; ++j) accs[n][j] = 0.f;
    __builtin_amdgcn_s_setprio(1);
#pragma unroll
    for (int kk = 0; kk < 2; ++kk)
#pragma unroll
      for (int n = 0; n < 4; ++n)
        accs[n] = __builtin_amdgcn_mfma_f32_16x16x32_bf16(ak[kk][n], qf[kk], accs[n], 0, 0, 0);
    __builtin_amdgcn_s_setprio(0);

    // ---- V fragments: issue now; softmax covers the L1/L2 latency ----
    bf16x8 av[2][4];
#pragma unroll
    for (int kk = 0; kk < 2; ++kk)
#pragma unroll
      for (int n = 0; n < 4; ++n)
        av[kk][n] = *(const bf16x8*)(vbase + (size_t)(n * 16) * SEQ + kvb + kk * 32);

    // ---- causal mask (only on diagonal tile) ----
    const int qg = qbase + wq + c;
    if (kt == qt) {
#pragma unroll
      for (int n = 0; n < 4; ++n)
#pragma unroll
        for (int jj = 0; jj < 4; ++jj)
          if (kvb + n * 16 + g * 4 + jj > qg) accs[n][jj] = MNEG;
    }

    // ---- online softmax, one q-row per lane; defer-max rescale (THR=8) ----
    float rm = accs[0][0];
#pragma unroll
    for (int n = 0; n < 4; ++n)
#pragma unroll
      for (int jj = 0; jj < 4; ++jj) rm = fmaxf(rm, accs[n][jj]);
    rm = fmaxf(rm, __shfl_xor(rm, 16));
    rm = fmaxf(rm, __shfl_xor(rm, 32));
    if (!__all(rm <= m_r + 8.f)) {
      const float mn = fmaxf(m_r, rm);
      const float al = exp2f((m_r - mn) * LOG2E);
      l_r *= al;
#pragma unroll
      for (int n = 0; n < 4; ++n)
#pragma unroll
        for (int jj = 0; jj < 4; ++jj) acco[n][jj] *= al;
      m_r = mn;
    }
    float rs = 0.f;
#pragma unroll
    for (int n = 0; n < 4; ++n)
#pragma unroll
      for (int jj = 0; jj < 4; ++jj) {
        const float pv = exp2f((accs[n][jj] - m_r) * LOG2E);
        accs[n][jj] = pv;
        rs += pv;
      }
    rs += __shfl_xor(rs, 16);
    rs += __shfl_xor(rs, 32);
    l_r += rs;

    // ---- P^T -> LDS (XOR-swizzled, wave-private rows) ----
#pragma unroll
    for (int n = 0; n < 4; ++n) {
      u16x4 pk4;
#pragma unroll
      for (int jj = 0; jj < 4; ++jj) pk4[jj] = f2bf(accs[n][jj]);
      *(u16x4*)&Ps[pr * 64 + ((n * 16 + g * 4) ^ px)] = pk4;
    }

    // ---- O^T += V^T P^T ----
    __builtin_amdgcn_s_setprio(1);
#pragma unroll
    for (int kk = 0; kk < 2; ++kk) {
      const bf16x8 pb = *(const bf16x8*)&Ps[pr * 64 + ((kk * 32 + g * 8) ^ px)];
#pragma unroll
      for (int n = 0; n < 4; ++n)
        acco[n] = __builtin_amdgcn_mfma_f32_16x16x32_bf16(av[kk][n], pb, acco[n], 0, 0, 0);
    }
    __builtin_amdgcn_s_setprio(0);
  }

  // ---- epilogue: O/l, store [B,S,H*64]; lane c owns row qbase+wq+c ----
  const float rl = 1.f / fmaxf(l_r, 1e-20f);
  const int b = bh >> 4, h = bh & 15;
  const int srow = qbase + wq + c;
#pragma unroll
  for (int n = 0; n < 4; ++n) {
    u16x4 pk;
#pragma unroll
    for (int jj = 0; jj < 4; ++jj) pk[jj] = f2bf(acco[n][jj] * rl);
    *(u16x4*)&o[(size_t)(b * SEQ + srow) * DMODEL + h * 64 + n * 16 + g * 4] = pk;
  }
}

// ---------------------------------------------------------------------------
extern "C" void kernel_launch(void* const* d_in, const int* in_sizes, int n_in,
                              void* d_out, int out_size, void* d_ws, size_t ws_size,
                              hipStream_t stream) {
  (void)in_sizes; (void)n_in; (void)out_size; (void)ws_size;
  const size_t MB = (size_t)1 << 20;
  char* ws = (char*)d_ws;
  unsigned short* xb  = (unsigned short*)(ws);            // 8 MB (reused as ow)
  unsigned short* Wqb = (unsigned short*)(ws + 8 * MB);   // 2 MB each
  unsigned short* Wkb = (unsigned short*)(ws + 10 * MB);
  unsigned short* Wvb = (unsigned short*)(ws + 12 * MB);
  unsigned short* Wob = (unsigned short*)(ws + 14 * MB);
  unsigned short* qw  = (unsigned short*)(ws + 16 * MB);  // 8 MB
  unsigned short* kw  = (unsigned short*)(ws + 24 * MB);  // 8 MB
  unsigned short* vtw = (unsigned short*)(ws + 32 * MB);  // 8 MB
  int* flags          = (int*)(ws + 40 * MB);
  float* tab          = (float*)(ws + 40 * MB + 4096);    // 1 MB cos/sin table
  unsigned short* ow  = xb;  // x dead after qkv_gemm

  const dim3 blk(256);
  probe_kernel<<<1, 64, 0, stream>>>((const unsigned int*)d_in[0], (const int*)d_in[5], flags);
  rope_table_kernel<<<512, blk, 0, stream>>>((const int*)d_in[5], flags, tab);
  conv_kernel<<<4096, blk, 0, stream>>>(d_in[0], d_in[1], d_in[2], d_in[3], d_in[4], xb, flags);
  qkv_gemm_kernel<<<dim3(32, 8, 3), blk, 0, stream>>>(xb, Wqb, Wkb, Wvb, qw, kw, vtw);
  rope_kernel<<<16384, blk, 0, stream>>>(qw, kw, tab);
  flash_kernel<<<dim3(1024), blk, 0, stream>>>(qw, kw, vtw, ow);
  out_gemm_kernel<<<dim3(64, 8), blk, 0, stream>>>(ow, Wob, d_out, flags);
}

// Round 10
// 136.878 us; speedup vs baseline: 1.6192x; 1.6192x over previous
//
#include <hip/hip_runtime.h>
#include <hip/hip_bf16.h>

#define DMODEL 1024
#define NHEADS 16
#define HDIM   64
#define BATCH  2
#define SEQ    2048
#define XELEMS ((size_t)BATCH * SEQ * DMODEL)   // 4,194,304
#define WELEMS ((size_t)DMODEL * DMODEL)        // 1,048,576

typedef __attribute__((ext_vector_type(8))) __bf16 bf16x8;
typedef __attribute__((ext_vector_type(4))) float  f32x4;
typedef __attribute__((ext_vector_type(2))) float  f32x2;
typedef __attribute__((ext_vector_type(4))) unsigned int   u32x4;
typedef __attribute__((ext_vector_type(4))) unsigned short u16x4;
typedef __attribute__((ext_vector_type(8))) unsigned short u16x8;

typedef const __attribute__((address_space(1))) void* gas_t;
typedef __attribute__((address_space(3))) void* las_t;

static __device__ __forceinline__ unsigned short f2bf(float f) {
  return __builtin_bit_cast(unsigned short, __float2bfloat16(f));
}
static __device__ __forceinline__ float bf2f(unsigned short u) {
  return __bfloat162float(__builtin_bit_cast(__hip_bfloat16, u));
}

// ---------------------------------------------------------------------------
// Dtype probe. flags[0]=1 iff float inputs are f32 (else bf16).
// flags[1]=1 iff token_positions is int64 (else int32).
// ---------------------------------------------------------------------------
__global__ __launch_bounds__(64) void probe_kernel(const unsigned int* __restrict__ x,
                                                   const int* __restrict__ pos,
                                                   int* __restrict__ flags) {
  const int lane = threadIdx.x;
  int bad = 0;
#pragma unroll
  for (int i = 0; i < 32; ++i) {
    const unsigned int u = x[lane * 32 + i];
    if (((u >> 23) & 0xFFu) == 0xFFu) bad++;
  }
  int zodd = 0;
#pragma unroll
  for (int i = 0; i < 4; ++i)
    if (pos[lane * 8 + 2 * i + 1] == 0) zodd++;
#pragma unroll
  for (int s = 1; s < 64; s <<= 1) {
    bad  += __shfl_xor(bad, s);
    zodd += __shfl_xor(zodd, s);
  }
  if (lane == 0) {
    flags[0] = (bad < 64) ? 1 : 0;    // 1 => f32 inputs
    flags[1] = (zodd >= 200) ? 1 : 0; // 1 => int64 positions
  }
}

// ---------------------------------------------------------------------------
// RoPE cos/sin table: per (b,s,pair) -> {cos, sin}. 131072 entries (1 MB).
// ---------------------------------------------------------------------------
__global__ __launch_bounds__(256) void rope_table_kernel(const int* __restrict__ pos,
                                                         const int* __restrict__ flags,
                                                         float* __restrict__ tab) {
  const int i = blockIdx.x * 256 + threadIdx.x;   // 0..131071
  const int pd = i & 31, rs = i >> 5;             // rs = b*SEQ + s
  const int pv = flags[1] ? pos[2 * rs] : pos[rs];
  const float ang = (float)pv * exp2f(-(float)pd * 0.41524101186092026f);
  f32x2 t; t[0] = cosf(ang); t[1] = sinf(ang);
  *(f32x2*)&tab[2 * i] = t;
}

// ---------------------------------------------------------------------------
// Canonicalize x,Wq,Wk,Wv,Wo into one contiguous bf16 buffer [x | Wq Wk Wv Wo].
// ---------------------------------------------------------------------------
__global__ __launch_bounds__(256) void conv_kernel(
    const void* __restrict__ x,
    const void* __restrict__ w0, const void* __restrict__ w1,
    const void* __restrict__ w2, const void* __restrict__ w3,
    unsigned short* __restrict__ dst, const int* __restrict__ flags) {
  const size_t e = ((size_t)blockIdx.x * 256 + threadIdx.x) * 8;
  const void* src;
  size_t off;
  if (e < XELEMS) { src = x; off = e; }
  else {
    const size_t r = e - XELEMS;
    const int wi = (int)(r >> 20);
    src = (wi == 0) ? w0 : (wi == 1) ? w1 : (wi == 2) ? w2 : w3;
    off = r & (WELEMS - 1);
  }
  if (flags[0]) {
    const float* s = (const float*)src + off;
    const f32x4 a = *(const f32x4*)(s);
    const f32x4 b = *(const f32x4*)(s + 4);
    u16x8 o8;
#pragma unroll
    for (int j = 0; j < 4; ++j) o8[j] = f2bf(a[j]);
#pragma unroll
    for (int j = 0; j < 4; ++j) o8[4 + j] = f2bf(b[j]);
    *(u16x8*)(dst + e) = o8;
  } else {
    *(u32x4*)(dst + e) = *(const u32x4*)((const unsigned short*)src + off);
  }
}

// ---------------------------------------------------------------------------
// Shared GEMM core (128x128 tile): 2-phase double-buffered LDS.
// ---------------------------------------------------------------------------
__device__ __forceinline__ void gemm_core(const unsigned short* __restrict__ Ag,
                                          const unsigned short* __restrict__ Bg,
                                          unsigned short* As, unsigned short* Bs,
                                          int bm, int bn, f32x4 acc[4][4]) {
  const int tid = threadIdx.x;
  const int lane = tid & 63;
  const int w  = tid >> 6;
  const int wm = w >> 1, wn = w & 1;
  const int c = lane & 15, g = lane >> 4;
  const int r0 = tid >> 2;
  const int s0 = (tid & 3) * 8;

  auto stage = [&](int buf, int k0) {
    unsigned short* ad = As + buf * 4096;
    unsigned short* bd = Bs + buf * 4096;
    __builtin_amdgcn_global_load_lds((gas_t)(Ag + (size_t)(bm + r0) * DMODEL + k0 + s0),
                                     (las_t)(ad + tid * 8), 16, 0, 0);
    __builtin_amdgcn_global_load_lds((gas_t)(Ag + (size_t)(bm + r0 + 64) * DMODEL + k0 + s0),
                                     (las_t)(ad + (tid + 256) * 8), 16, 0, 0);
    __builtin_amdgcn_global_load_lds((gas_t)(Bg + (size_t)(bn + r0) * DMODEL + k0 + s0),
                                     (las_t)(bd + tid * 8), 16, 0, 0);
    __builtin_amdgcn_global_load_lds((gas_t)(Bg + (size_t)(bn + r0 + 64) * DMODEL + k0 + s0),
                                     (las_t)(bd + (tid + 256) * 8), 16, 0, 0);
  };

  stage(0, 0);
  __syncthreads();
  for (int k0 = 0; k0 < DMODEL; k0 += 32) {
    const int cur = (k0 >> 5) & 1;
    if (k0 + 32 < DMODEL) stage(cur ^ 1, k0 + 32);
    const unsigned short* ar = As + cur * 4096;
    const unsigned short* br = Bs + cur * 4096;
    bf16x8 af[4], bfr[4];
#pragma unroll
    for (int m = 0; m < 4; ++m)
      af[m] = *(const bf16x8*)&ar[(wm * 64 + m * 16 + c) * 32 + g * 8];
#pragma unroll
    for (int n = 0; n < 4; ++n)
      bfr[n] = *(const bf16x8*)&br[(wn * 64 + n * 16 + c) * 32 + g * 8];
    __builtin_amdgcn_s_setprio(1);
#pragma unroll
    for (int m = 0; m < 4; ++m)
#pragma unroll
      for (int n = 0; n < 4; ++n)
        acc[m][n] = __builtin_amdgcn_mfma_f32_16x16x32_bf16(af[m], bfr[n], acc[m][n], 0, 0, 0);
    __builtin_amdgcn_s_setprio(0);
    __syncthreads();
  }
}

// ---------------------------------------------------------------------------
// QKV projection. grid = (32, 8, 3). Q,K stored [B,H,S,64]; V stored
// transposed [B,H,64,S].
// ---------------------------------------------------------------------------
__global__ __launch_bounds__(256) void qkv_gemm_kernel(
    const unsigned short* __restrict__ x,
    const unsigned short* __restrict__ Wq, const unsigned short* __restrict__ Wk,
    const unsigned short* __restrict__ Wv,
    unsigned short* __restrict__ qo, unsigned short* __restrict__ ko,
    unsigned short* __restrict__ vto) {
  __shared__ unsigned short As[2 * 128 * 32];
  __shared__ unsigned short Bs[2 * 128 * 32];
  const int z = blockIdx.z;
  const unsigned short* W = (z == 0) ? Wq : (z == 1) ? Wk : Wv;
  const int bm = blockIdx.x * 128, bn = blockIdx.y * 128;
  f32x4 acc[4][4];
#pragma unroll
  for (int m = 0; m < 4; ++m)
#pragma unroll
    for (int n = 0; n < 4; ++n)
#pragma unroll
      for (int j = 0; j < 4; ++j) acc[m][n][j] = 0.f;

  gemm_core(x, W, As, Bs, bm, bn, acc);

  const int tid = threadIdx.x, lane = tid & 63, w = tid >> 6;
  const int wm = w >> 1, wn = w & 1, c = lane & 15, g4 = lane >> 4;
#pragma unroll
  for (int m = 0; m < 4; ++m) {
#pragma unroll
    for (int n = 0; n < 4; ++n) {
      const int col = bn + wn * 64 + n * 16 + c;
      const int h = col >> 6, d = col & 63;
      const int row0 = bm + wm * 64 + m * 16 + g4 * 4;
      if (z == 2) {
        const int b = row0 >> 11, s0 = row0 & (SEQ - 1);
        u16x4 pk;
#pragma unroll
        for (int j = 0; j < 4; ++j) pk[j] = f2bf(acc[m][n][j]);
        *(u16x4*)&vto[((size_t)(b * NHEADS + h) * HDIM + d) * SEQ + s0] = pk;
      } else {
        unsigned short* dst = z ? ko : qo;
#pragma unroll
        for (int j = 0; j < 4; ++j) {
          const int row = row0 + j;
          const int b = row >> 11, s = row & (SEQ - 1);
          dst[((size_t)(b * NHEADS + h) * SEQ + s) * HDIM + d] = f2bf(acc[m][n][j]);
        }
      }
    }
  }
}

// ---------------------------------------------------------------------------
// Output projection, 64x128 tile: out = O[4096x1024] * Wo^T. grid (64,8).
// ---------------------------------------------------------------------------
__global__ __launch_bounds__(256) void out_gemm_kernel(
    const unsigned short* __restrict__ A, const unsigned short* __restrict__ Wo,
    void* __restrict__ outv, const int* __restrict__ flags) {
  __shared__ unsigned short As[2 * 64 * 32];
  __shared__ unsigned short Bs[2 * 128 * 32];
  const int bm = blockIdx.x * 64, bn = blockIdx.y * 128;
  const int tid = threadIdx.x, lane = tid & 63, w = tid >> 6;
  const int c = lane & 15, g = lane >> 4;
  const int r0 = tid >> 2, s0 = (tid & 3) * 8;
  f32x4 acc[4][2];
#pragma unroll
  for (int m = 0; m < 4; ++m)
#pragma unroll
    for (int n = 0; n < 2; ++n)
#pragma unroll
      for (int j = 0; j < 4; ++j) acc[m][n][j] = 0.f;

  auto stage = [&](int buf, int k0) {
    __builtin_amdgcn_global_load_lds((gas_t)(A + (size_t)(bm + r0) * DMODEL + k0 + s0),
                                     (las_t)(As + buf * 2048 + tid * 8), 16, 0, 0);
    __builtin_amdgcn_global_load_lds((gas_t)(Wo + (size_t)(bn + r0) * DMODEL + k0 + s0),
                                     (las_t)(Bs + buf * 4096 + tid * 8), 16, 0, 0);
    __builtin_amdgcn_global_load_lds((gas_t)(Wo + (size_t)(bn + r0 + 64) * DMODEL + k0 + s0),
                                     (las_t)(Bs + buf * 4096 + (tid + 256) * 8), 16, 0, 0);
  };

  stage(0, 0);
  __syncthreads();
  for (int k0 = 0; k0 < DMODEL; k0 += 32) {
    const int cur = (k0 >> 5) & 1;
    if (k0 + 32 < DMODEL) stage(cur ^ 1, k0 + 32);
    const unsigned short* ar = As + cur * 2048;
    const unsigned short* br = Bs + cur * 4096;
    bf16x8 af[4], bfr[2];
#pragma unroll
    for (int m = 0; m < 4; ++m)
      af[m] = *(const bf16x8*)&ar[(m * 16 + c) * 32 + g * 8];
#pragma unroll
    for (int n = 0; n < 2; ++n)
      bfr[n] = *(const bf16x8*)&br[(w * 32 + n * 16 + c) * 32 + g * 8];
    __builtin_amdgcn_s_setprio(1);
#pragma unroll
    for (int m = 0; m < 4; ++m)
#pragma unroll
      for (int n = 0; n < 2; ++n)
        acc[m][n] = __builtin_amdgcn_mfma_f32_16x16x32_bf16(af[m], bfr[n], acc[m][n], 0, 0, 0);
    __builtin_amdgcn_s_setprio(0);
    __syncthreads();
  }

  const int f32o = flags[0];
  if (f32o) {
    float* out = (float*)outv;
#pragma unroll
    for (int m = 0; m < 4; ++m)
#pragma unroll
      for (int n = 0; n < 2; ++n) {
        const int col = bn + w * 32 + n * 16 + c;
#pragma unroll
        for (int j = 0; j < 4; ++j) {
          const int row = bm + m * 16 + g * 4 + j;
          out[(size_t)row * DMODEL + col] = acc[m][n][j];
        }
      }
  } else {
    unsigned short* out = (unsigned short*)outv;
#pragma unroll
    for (int m = 0; m < 4; ++m)
#pragma unroll
      for (int n = 0; n < 2; ++n) {
        const int col = bn + w * 32 + n * 16 + c;
#pragma unroll
        for (int j = 0; j < 4; ++j) {
          const int row = bm + m * 16 + g * 4 + j;
          out[(size_t)row * DMODEL + col] = f2bf(acc[m][n][j]);
        }
      }
  }
}

// ---------------------------------------------------------------------------
// RoPE in-place on Q and K ([B,H,S,64]) via precomputed cos/sin table.
// Q pre-scaled by 0.125.
// ---------------------------------------------------------------------------
__global__ __launch_bounds__(256) void rope_kernel(unsigned short* __restrict__ q,
                                                   unsigned short* __restrict__ k,
                                                   const float* __restrict__ tab) {
  const int idx = blockIdx.x * 256 + threadIdx.x;
  const int tsel = idx >> 21;
  const int p = idx & ((1 << 21) - 1);
  const int j = p & 31;
  const int s = (p >> 5) & (SEQ - 1);
  const int bh = p >> 16;
  const int b = bh >> 4;
  unsigned short* base = tsel ? k : q;
  const float sc = tsel ? 1.0f : 0.125f;
  const f32x2 t = *(const f32x2*)&tab[(((size_t)(b * SEQ + s)) * 32 + j) * 2];
  const float cs = t[0], sn = t[1];
  unsigned int* wp = (unsigned int*)base + ((p >> 5) * 32 + j);
  const unsigned int u = *wp;
  const float e = bf2f((unsigned short)(u & 0xffffu));
  const float o = bf2f((unsigned short)(u >> 16));
  *wp = (unsigned int)f2bf((e * cs - o * sn) * sc) |
        ((unsigned int)f2bf((e * sn + o * cs) * sc) << 16);
}

// ---------------------------------------------------------------------------
// Flash attention v8 — round-8 LDS structure, but each wave owns 32 q-rows
// (two 16-row groups m=0,1). QBLK=128, 4 waves, 512 blocks. K-frags read once
// from LDS and shared by both row-groups; two independent softmax chains
// interleave (ILP). K+V double-buffered, one barrier per tile, defer-max.
// ---------------------------------------------------------------------------
#define MNEG -1e30f
#define LOG2E 1.4426950408889634f

template<int BUF>
__device__ __forceinline__ void flash_tile(
    int kt, int nkv, int qt, int qbase, int wq32, int c, int g, int tid,
    const unsigned short* (&kp)[2], const unsigned short* (&vp)[2],
    unsigned short (&Ks)[2][64 * 64], unsigned short (&Vs)[2][64 * 64],
    unsigned short (&Ps)[128 * 64],
    const bf16x8 (&qf)[2][2], f32x4 (&acco)[2][4],
    float (&m_r)[2], float (&l_r)[2]) {
  const int kvb = kt * 64;
  // ---- prefetch next K/V tile into buffer BUF^1 (landed by end barrier) ----
  if (kt + 1 < nkv) {
#pragma unroll
    for (int i = 0; i < 2; ++i) {
      const int t8 = (tid + i * 256) * 8;
      __builtin_amdgcn_global_load_lds((gas_t)kp[i], (las_t)(Ks[BUF ^ 1] + t8), 16, 0, 0);
      __builtin_amdgcn_global_load_lds((gas_t)vp[i], (las_t)(Vs[BUF ^ 1] + t8), 16, 0, 0);
      kp[i] += 64 * HDIM;   // next K tile: +64 rows
      vp[i] += 64;          // next V^T tile: +64 cols
    }
  }

  // ---- K fragments from LDS once, shared by both row-groups ----
  bf16x8 ak[2][4];
#pragma unroll
  for (int kk = 0; kk < 2; ++kk)
#pragma unroll
    for (int n = 0; n < 4; ++n) {
      const int r = n * 16 + c;
      const int sl = (kk * 4 + g) ^ (r & 7);
      ak[kk][n] = *(const bf16x8*)&Ks[BUF][r * 64 + sl * 8];
    }

  // ---- S^T = K Q^T for both row-groups ----
  f32x4 accs[2][4];
#pragma unroll
  for (int m = 0; m < 2; ++m)
#pragma unroll
    for (int n = 0; n < 4; ++n)
#pragma unroll
      for (int j = 0; j < 4; ++j) accs[m][n][j] = 0.f;
  __builtin_amdgcn_s_setprio(1);
#pragma unroll
  for (int kk = 0; kk < 2; ++kk)
#pragma unroll
    for (int n = 0; n < 4; ++n)
#pragma unroll
      for (int m = 0; m < 2; ++m)
        accs[m][n] = __builtin_amdgcn_mfma_f32_16x16x32_bf16(ak[kk][n], qf[m][kk], accs[m][n], 0, 0, 0);
  __builtin_amdgcn_s_setprio(0);

  // ---- V fragments from LDS (latency hidden under mask+softmax) ----
  bf16x8 av[2][4];
#pragma unroll
  for (int kk = 0; kk < 2; ++kk)
#pragma unroll
    for (int n = 0; n < 4; ++n) {
      const int r = n * 16 + c;
      const int sl = (kk * 4 + g) ^ (r & 7);
      av[kk][n] = *(const bf16x8*)&Vs[BUF][r * 64 + sl * 8];
    }

  // ---- causal mask (tiles intersecting the 128-row diagonal band) ----
  if (kt >= 2 * qt) {
#pragma unroll
    for (int m = 0; m < 2; ++m) {
      const int qg = qbase + wq32 + m * 16 + c;
#pragma unroll
      for (int n = 0; n < 4; ++n)
#pragma unroll
        for (int jj = 0; jj < 4; ++jj)
          if (kvb + n * 16 + g * 4 + jj > qg) accs[m][n][jj] = MNEG;
    }
  }

  // ---- online softmax per row-group (independent chains) ----
#pragma unroll
  for (int m = 0; m < 2; ++m) {
    float rm = accs[m][0][0];
#pragma unroll
    for (int n = 0; n < 4; ++n)
#pragma unroll
      for (int jj = 0; jj < 4; ++jj) rm = fmaxf(rm, accs[m][n][jj]);
    rm = fmaxf(rm, __shfl_xor(rm, 16));
    rm = fmaxf(rm, __shfl_xor(rm, 32));
    if (!__all(rm <= m_r[m] + 8.f)) {
      const float mn = fmaxf(m_r[m], rm);
      const float al = exp2f((m_r[m] - mn) * LOG2E);
      l_r[m] *= al;
#pragma unroll
      for (int n = 0; n < 4; ++n)
#pragma unroll
        for (int jj = 0; jj < 4; ++jj) acco[m][n][jj] *= al;
      m_r[m] = mn;
    }
    float rs = 0.f;
#pragma unroll
    for (int n = 0; n < 4; ++n)
#pragma unroll
      for (int jj = 0; jj < 4; ++jj) {
        const float pv = exp2f((accs[m][n][jj] - m_r[m]) * LOG2E);
        accs[m][n][jj] = pv;
        rs += pv;
      }
    rs += __shfl_xor(rs, 16);
    rs += __shfl_xor(rs, 32);
    l_r[m] += rs;

    // ---- P^T -> LDS (XOR-swizzled, wave-private rows) ----
    const int pr = wq32 + m * 16 + c;
    const int px = (pr & 7) << 3;
#pragma unroll
    for (int n = 0; n < 4; ++n) {
      u16x4 pk4;
#pragma unroll
      for (int jj = 0; jj < 4; ++jj) pk4[jj] = f2bf(accs[m][n][jj]);
      *(u16x4*)&Ps[pr * 64 + ((n * 16 + g * 4) ^ px)] = pk4;
    }
  }

  // ---- O^T += V^T P^T for both row-groups ----
  __builtin_amdgcn_s_setprio(1);
#pragma unroll
  for (int kk = 0; kk < 2; ++kk)
#pragma unroll
    for (int m = 0; m < 2; ++m) {
      const int pr = wq32 + m * 16 + c;
      const int px = (pr & 7) << 3;
      const bf16x8 pb = *(const bf16x8*)&Ps[pr * 64 + ((kk * 32 + g * 8) ^ px)];
#pragma unroll
      for (int n = 0; n < 4; ++n)
        acco[m][n] = __builtin_amdgcn_mfma_f32_16x16x32_bf16(av[kk][n], pb, acco[m][n], 0, 0, 0);
    }
  __builtin_amdgcn_s_setprio(0);
  __syncthreads();  // drains prefetch vmcnt; publishes BUF^1; protects buffers
}

__global__ __launch_bounds__(256, 2) void flash_kernel(
    const unsigned short* __restrict__ q, const unsigned short* __restrict__ k,
    const unsigned short* __restrict__ vt, unsigned short* __restrict__ o) {
  __shared__ unsigned short Ks[2][64 * 64];   // 16 KB double-buffered
  __shared__ unsigned short Vs[2][64 * 64];   // 16 KB double-buffered
  __shared__ unsigned short Ps[128 * 64];     // 16 KB XOR-swizzled

  const int wg = blockIdx.x;                  // 0..511, sorted big-first
  const int qt = (SEQ / 128 - 1) - (wg >> 5); // q-tile of 128 rows
  const int bh = wg & 31;
  const int qbase = qt * 128;
  const int tid = threadIdx.x, lane = tid & 63, w = tid >> 6;
  const int c = lane & 15, g = lane >> 4;
  const int wq32 = w * 32;                    // wave owns rows [wq32, wq32+32)
  const size_t tb = (size_t)bh * SEQ * HDIM;

  // ---- Q fragments direct to registers (q pre-scaled by 0.125 in rope) ----
  bf16x8 qf[2][2];
#pragma unroll
  for (int m = 0; m < 2; ++m)
#pragma unroll
    for (int kk = 0; kk < 2; ++kk)
      qf[m][kk] = *(const bf16x8*)(q + tb + (size_t)(qbase + wq32 + m * 16 + c) * HDIM +
                                   kk * 32 + g * 8);

  // ---- persistent staging pointers (pre-swizzled source) ----
  const unsigned short* kp[2];
  const unsigned short* vp[2];
#pragma unroll
  for (int i = 0; i < 2; ++i) {
    const int t = tid + i * 256;
    const int r = t >> 3;
    const int sl = (t & 7) ^ (r & 7);
    kp[i] = k + tb + (size_t)r * HDIM + sl * 8;
    vp[i] = vt + tb + (size_t)r * SEQ + sl * 8;
  }
  // ---- stage tile 0 into buffer 0; advance pointers to tile 1 ----
#pragma unroll
  for (int i = 0; i < 2; ++i) {
    const int t8 = (tid + i * 256) * 8;
    __builtin_amdgcn_global_load_lds((gas_t)kp[i], (las_t)(Ks[0] + t8), 16, 0, 0);
    __builtin_amdgcn_global_load_lds((gas_t)vp[i], (las_t)(Vs[0] + t8), 16, 0, 0);
    kp[i] += 64 * HDIM;
    vp[i] += 64;
  }
  __syncthreads();

  f32x4 acco[2][4];
#pragma unroll
  for (int m = 0; m < 2; ++m)
#pragma unroll
    for (int n = 0; n < 4; ++n)
#pragma unroll
      for (int j = 0; j < 4; ++j) acco[m][n][j] = 0.f;
  float m_r[2] = {MNEG, MNEG}, l_r[2] = {0.f, 0.f};

  const int nkv = 2 * qt + 2;   // always even
  for (int kt = 0; kt < nkv; kt += 2) {
    flash_tile<0>(kt,     nkv, qt, qbase, wq32, c, g, tid, kp, vp, Ks, Vs, Ps, qf, acco, m_r, l_r);
    flash_tile<1>(kt + 1, nkv, qt, qbase, wq32, c, g, tid, kp, vp, Ks, Vs, Ps, qf, acco, m_r, l_r);
  }

  // ---- epilogue: O/l, store [B,S,H*64]; lane c owns its rows ----
  const int b = bh >> 4, h = bh & 15;
#pragma unroll
  for (int m = 0; m < 2; ++m) {
    const float rl = 1.f / fmaxf(l_r[m], 1e-20f);
    const int srow = qbase + wq32 + m * 16 + c;
#pragma unroll
    for (int n = 0; n < 4; ++n) {
      u16x4 pk;
#pragma unroll
      for (int jj = 0; jj < 4; ++jj) pk[jj] = f2bf(acco[m][n][jj] * rl);
      *(u16x4*)&o[(size_t)(b * SEQ + srow) * DMODEL + h * 64 + n * 16 + g * 4] = pk;
    }
  }
}

// ---------------------------------------------------------------------------
extern "C" void kernel_launch(void* const* d_in, const int* in_sizes, int n_in,
                              void* d_out, int out_size, void* d_ws, size_t ws_size,
                              hipStream_t stream) {
  (void)in_sizes; (void)n_in; (void)out_size; (void)ws_size;
  const size_t MB = (size_t)1 << 20;
  char* ws = (char*)d_ws;
  unsigned short* xb  = (unsigned short*)(ws);            // 8 MB (reused as ow)
  unsigned short* Wqb = (unsigned short*)(ws + 8 * MB);   // 2 MB each
  unsigned short* Wkb = (unsigned short*)(ws + 10 * MB);
  unsigned short* Wvb = (unsigned short*)(ws + 12 * MB);
  unsigned short* Wob = (unsigned short*)(ws + 14 * MB);
  unsigned short* qw  = (unsigned short*)(ws + 16 * MB);  // 8 MB
  unsigned short* kw  = (unsigned short*)(ws + 24 * MB);  // 8 MB
  unsigned short* vtw = (unsigned short*)(ws + 32 * MB);  // 8 MB
  int* flags          = (int*)(ws + 40 * MB);
  float* tab          = (float*)(ws + 40 * MB + 4096);    // 1 MB cos/sin table
  unsigned short* ow  = xb;  // x dead after qkv_gemm

  const dim3 blk(256);
  probe_kernel<<<1, 64, 0, stream>>>((const unsigned int*)d_in[0], (const int*)d_in[5], flags);
  rope_table_kernel<<<512, blk, 0, stream>>>((const int*)d_in[5], flags, tab);
  conv_kernel<<<4096, blk, 0, stream>>>(d_in[0], d_in[1], d_in[2], d_in[3], d_in[4], xb, flags);
  qkv_gemm_kernel<<<dim3(32, 8, 3), blk, 0, stream>>>(xb, Wqb, Wkb, Wvb, qw, kw, vtw);
  rope_kernel<<<16384, blk, 0, stream>>>(qw, kw, tab);
  flash_kernel<<<dim3(512), blk, 0, stream>>>(qw, kw, vtw, ow);
  out_gemm_kernel<<<dim3(64, 8), blk, 0, stream>>>(ow, Wob, d_out, flags);
}

// Round 11
// 121.331 us; speedup vs baseline: 1.8266x; 1.1281x over previous
//
#include <hip/hip_runtime.h>
#include <hip/hip_bf16.h>

#define DMODEL 1024
#define NHEADS 16
#define HDIM   64
#define BATCH  2
#define SEQ    2048
#define XELEMS ((size_t)BATCH * SEQ * DMODEL)   // 4,194,304
#define WELEMS ((size_t)DMODEL * DMODEL)        // 1,048,576

typedef __attribute__((ext_vector_type(8))) __bf16 bf16x8;
typedef __attribute__((ext_vector_type(4))) float  f32x4;
typedef __attribute__((ext_vector_type(2))) float  f32x2;
typedef __attribute__((ext_vector_type(4))) unsigned int   u32x4;
typedef __attribute__((ext_vector_type(4))) unsigned short u16x4;
typedef __attribute__((ext_vector_type(8))) unsigned short u16x8;

typedef const __attribute__((address_space(1))) void* gas_t;
typedef __attribute__((address_space(3))) void* las_t;

static __device__ __forceinline__ unsigned short f2bf(float f) {
  return __builtin_bit_cast(unsigned short, __float2bfloat16(f));
}
static __device__ __forceinline__ float bf2f(unsigned short u) {
  return __bfloat162float(__builtin_bit_cast(__hip_bfloat16, u));
}

// ---------------------------------------------------------------------------
// Dtype probe. flags[0]=1 iff float inputs are f32 (else bf16).
// flags[1]=1 iff token_positions is int64 (else int32).
// ---------------------------------------------------------------------------
__global__ __launch_bounds__(64) void probe_kernel(const unsigned int* __restrict__ x,
                                                   const int* __restrict__ pos,
                                                   int* __restrict__ flags) {
  const int lane = threadIdx.x;
  int bad = 0;
#pragma unroll
  for (int i = 0; i < 32; ++i) {
    const unsigned int u = x[lane * 32 + i];
    if (((u >> 23) & 0xFFu) == 0xFFu) bad++;
  }
  int zodd = 0;
#pragma unroll
  for (int i = 0; i < 4; ++i)
    if (pos[lane * 8 + 2 * i + 1] == 0) zodd++;
#pragma unroll
  for (int s = 1; s < 64; s <<= 1) {
    bad  += __shfl_xor(bad, s);
    zodd += __shfl_xor(zodd, s);
  }
  if (lane == 0) {
    flags[0] = (bad < 64) ? 1 : 0;    // 1 => f32 inputs
    flags[1] = (zodd >= 200) ? 1 : 0; // 1 => int64 positions
  }
}

// ---------------------------------------------------------------------------
// RoPE cos/sin table: per (b,s,pair) -> {cos, sin}. 131072 entries (1 MB).
// ---------------------------------------------------------------------------
__global__ __launch_bounds__(256) void rope_table_kernel(const int* __restrict__ pos,
                                                         const int* __restrict__ flags,
                                                         float* __restrict__ tab) {
  const int i = blockIdx.x * 256 + threadIdx.x;   // 0..131071
  const int pd = i & 31, rs = i >> 5;             // rs = b*SEQ + s
  const int pv = flags[1] ? pos[2 * rs] : pos[rs];
  const float ang = (float)pv * exp2f(-(float)pd * 0.41524101186092026f);
  f32x2 t; t[0] = cosf(ang); t[1] = sinf(ang);
  *(f32x2*)&tab[2 * i] = t;
}

// ---------------------------------------------------------------------------
// Canonicalize x,Wq,Wk,Wv,Wo into one contiguous bf16 buffer [x | Wq Wk Wv Wo].
// ---------------------------------------------------------------------------
__global__ __launch_bounds__(256) void conv_kernel(
    const void* __restrict__ x,
    const void* __restrict__ w0, const void* __restrict__ w1,
    const void* __restrict__ w2, const void* __restrict__ w3,
    unsigned short* __restrict__ dst, const int* __restrict__ flags) {
  const size_t e = ((size_t)blockIdx.x * 256 + threadIdx.x) * 8;
  const void* src;
  size_t off;
  if (e < XELEMS) { src = x; off = e; }
  else {
    const size_t r = e - XELEMS;
    const int wi = (int)(r >> 20);
    src = (wi == 0) ? w0 : (wi == 1) ? w1 : (wi == 2) ? w2 : w3;
    off = r & (WELEMS - 1);
  }
  if (flags[0]) {
    const float* s = (const float*)src + off;
    const f32x4 a = *(const f32x4*)(s);
    const f32x4 b = *(const f32x4*)(s + 4);
    u16x8 o8;
#pragma unroll
    for (int j = 0; j < 4; ++j) o8[j] = f2bf(a[j]);
#pragma unroll
    for (int j = 0; j < 4; ++j) o8[4 + j] = f2bf(b[j]);
    *(u16x8*)(dst + e) = o8;
  } else {
    *(u32x4*)(dst + e) = *(const u32x4*)((const unsigned short*)src + off);
  }
}

// ---------------------------------------------------------------------------
// Shared GEMM core (128x128 tile): 2-phase double-buffered LDS.
// ---------------------------------------------------------------------------
__device__ __forceinline__ void gemm_core(const unsigned short* __restrict__ Ag,
                                          const unsigned short* __restrict__ Bg,
                                          unsigned short* As, unsigned short* Bs,
                                          int bm, int bn, f32x4 acc[4][4]) {
  const int tid = threadIdx.x;
  const int lane = tid & 63;
  const int w  = tid >> 6;
  const int wm = w >> 1, wn = w & 1;
  const int c = lane & 15, g = lane >> 4;
  const int r0 = tid >> 2;
  const int s0 = (tid & 3) * 8;

  auto stage = [&](int buf, int k0) {
    unsigned short* ad = As + buf * 4096;
    unsigned short* bd = Bs + buf * 4096;
    __builtin_amdgcn_global_load_lds((gas_t)(Ag + (size_t)(bm + r0) * DMODEL + k0 + s0),
                                     (las_t)(ad + tid * 8), 16, 0, 0);
    __builtin_amdgcn_global_load_lds((gas_t)(Ag + (size_t)(bm + r0 + 64) * DMODEL + k0 + s0),
                                     (las_t)(ad + (tid + 256) * 8), 16, 0, 0);
    __builtin_amdgcn_global_load_lds((gas_t)(Bg + (size_t)(bn + r0) * DMODEL + k0 + s0),
                                     (las_t)(bd + tid * 8), 16, 0, 0);
    __builtin_amdgcn_global_load_lds((gas_t)(Bg + (size_t)(bn + r0 + 64) * DMODEL + k0 + s0),
                                     (las_t)(bd + (tid + 256) * 8), 16, 0, 0);
  };

  stage(0, 0);
  __syncthreads();
  for (int k0 = 0; k0 < DMODEL; k0 += 32) {
    const int cur = (k0 >> 5) & 1;
    if (k0 + 32 < DMODEL) stage(cur ^ 1, k0 + 32);
    const unsigned short* ar = As + cur * 4096;
    const unsigned short* br = Bs + cur * 4096;
    bf16x8 af[4], bfr[4];
#pragma unroll
    for (int m = 0; m < 4; ++m)
      af[m] = *(const bf16x8*)&ar[(wm * 64 + m * 16 + c) * 32 + g * 8];
#pragma unroll
    for (int n = 0; n < 4; ++n)
      bfr[n] = *(const bf16x8*)&br[(wn * 64 + n * 16 + c) * 32 + g * 8];
    __builtin_amdgcn_s_setprio(1);
#pragma unroll
    for (int m = 0; m < 4; ++m)
#pragma unroll
      for (int n = 0; n < 4; ++n)
        acc[m][n] = __builtin_amdgcn_mfma_f32_16x16x32_bf16(af[m], bfr[n], acc[m][n], 0, 0, 0);
    __builtin_amdgcn_s_setprio(0);
    __syncthreads();
  }
}

// ---------------------------------------------------------------------------
// QKV projection. grid = (32, 8, 3). Q,K stored [B,H,S,64]; V stored
// transposed [B,H,64,S]. Q stored RAW (rope applied in-register in flash).
// ---------------------------------------------------------------------------
__global__ __launch_bounds__(256) void qkv_gemm_kernel(
    const unsigned short* __restrict__ x,
    const unsigned short* __restrict__ Wq, const unsigned short* __restrict__ Wk,
    const unsigned short* __restrict__ Wv,
    unsigned short* __restrict__ qo, unsigned short* __restrict__ ko,
    unsigned short* __restrict__ vto) {
  __shared__ unsigned short As[2 * 128 * 32];
  __shared__ unsigned short Bs[2 * 128 * 32];
  const int z = blockIdx.z;
  const unsigned short* W = (z == 0) ? Wq : (z == 1) ? Wk : Wv;
  const int bm = blockIdx.x * 128, bn = blockIdx.y * 128;
  f32x4 acc[4][4];
#pragma unroll
  for (int m = 0; m < 4; ++m)
#pragma unroll
    for (int n = 0; n < 4; ++n)
#pragma unroll
      for (int j = 0; j < 4; ++j) acc[m][n][j] = 0.f;

  gemm_core(x, W, As, Bs, bm, bn, acc);

  const int tid = threadIdx.x, lane = tid & 63, w = tid >> 6;
  const int wm = w >> 1, wn = w & 1, c = lane & 15, g4 = lane >> 4;
#pragma unroll
  for (int m = 0; m < 4; ++m) {
#pragma unroll
    for (int n = 0; n < 4; ++n) {
      const int col = bn + wn * 64 + n * 16 + c;
      const int h = col >> 6, d = col & 63;
      const int row0 = bm + wm * 64 + m * 16 + g4 * 4;
      if (z == 2) {
        const int b = row0 >> 11, s0 = row0 & (SEQ - 1);
        u16x4 pk;
#pragma unroll
        for (int j = 0; j < 4; ++j) pk[j] = f2bf(acc[m][n][j]);
        *(u16x4*)&vto[((size_t)(b * NHEADS + h) * HDIM + d) * SEQ + s0] = pk;
      } else {
        unsigned short* dst = z ? ko : qo;
#pragma unroll
        for (int j = 0; j < 4; ++j) {
          const int row = row0 + j;
          const int b = row >> 11, s = row & (SEQ - 1);
          dst[((size_t)(b * NHEADS + h) * SEQ + s) * HDIM + d] = f2bf(acc[m][n][j]);
        }
      }
    }
  }
}

// ---------------------------------------------------------------------------
// Output projection, 64x128 tile: out = O[4096x1024] * Wo^T. grid (64,8).
// ---------------------------------------------------------------------------
__global__ __launch_bounds__(256) void out_gemm_kernel(
    const unsigned short* __restrict__ A, const unsigned short* __restrict__ Wo,
    void* __restrict__ outv, const int* __restrict__ flags) {
  __shared__ unsigned short As[2 * 64 * 32];
  __shared__ unsigned short Bs[2 * 128 * 32];
  const int bm = blockIdx.x * 64, bn = blockIdx.y * 128;
  const int tid = threadIdx.x, lane = tid & 63, w = tid >> 6;
  const int c = lane & 15, g = lane >> 4;
  const int r0 = tid >> 2, s0 = (tid & 3) * 8;
  f32x4 acc[4][2];
#pragma unroll
  for (int m = 0; m < 4; ++m)
#pragma unroll
    for (int n = 0; n < 2; ++n)
#pragma unroll
      for (int j = 0; j < 4; ++j) acc[m][n][j] = 0.f;

  auto stage = [&](int buf, int k0) {
    __builtin_amdgcn_global_load_lds((gas_t)(A + (size_t)(bm + r0) * DMODEL + k0 + s0),
                                     (las_t)(As + buf * 2048 + tid * 8), 16, 0, 0);
    __builtin_amdgcn_global_load_lds((gas_t)(Wo + (size_t)(bn + r0) * DMODEL + k0 + s0),
                                     (las_t)(Bs + buf * 4096 + tid * 8), 16, 0, 0);
    __builtin_amdgcn_global_load_lds((gas_t)(Wo + (size_t)(bn + r0 + 64) * DMODEL + k0 + s0),
                                     (las_t)(Bs + buf * 4096 + (tid + 256) * 8), 16, 0, 0);
  };

  stage(0, 0);
  __syncthreads();
  for (int k0 = 0; k0 < DMODEL; k0 += 32) {
    const int cur = (k0 >> 5) & 1;
    if (k0 + 32 < DMODEL) stage(cur ^ 1, k0 + 32);
    const unsigned short* ar = As + cur * 2048;
    const unsigned short* br = Bs + cur * 4096;
    bf16x8 af[4], bfr[2];
#pragma unroll
    for (int m = 0; m < 4; ++m)
      af[m] = *(const bf16x8*)&ar[(m * 16 + c) * 32 + g * 8];
#pragma unroll
    for (int n = 0; n < 2; ++n)
      bfr[n] = *(const bf16x8*)&br[(w * 32 + n * 16 + c) * 32 + g * 8];
    __builtin_amdgcn_s_setprio(1);
#pragma unroll
    for (int m = 0; m < 4; ++m)
#pragma unroll
      for (int n = 0; n < 2; ++n)
        acc[m][n] = __builtin_amdgcn_mfma_f32_16x16x32_bf16(af[m], bfr[n], acc[m][n], 0, 0, 0);
    __builtin_amdgcn_s_setprio(0);
    __syncthreads();
  }

  const int f32o = flags[0];
  if (f32o) {
    float* out = (float*)outv;
#pragma unroll
    for (int m = 0; m < 4; ++m)
#pragma unroll
      for (int n = 0; n < 2; ++n) {
        const int col = bn + w * 32 + n * 16 + c;
#pragma unroll
        for (int j = 0; j < 4; ++j) {
          const int row = bm + m * 16 + g * 4 + j;
          out[(size_t)row * DMODEL + col] = acc[m][n][j];
        }
      }
  } else {
    unsigned short* out = (unsigned short*)outv;
#pragma unroll
    for (int m = 0; m < 4; ++m)
#pragma unroll
      for (int n = 0; n < 2; ++n) {
        const int col = bn + w * 32 + n * 16 + c;
#pragma unroll
        for (int j = 0; j < 4; ++j) {
          const int row = bm + m * 16 + g * 4 + j;
          out[(size_t)row * DMODEL + col] = f2bf(acc[m][n][j]);
        }
      }
  }
}

// ---------------------------------------------------------------------------
// RoPE in-place on K ONLY ([B,H,S,64]) via cos/sin table. (Q is roped
// in-register inside flash.) 2^21 pairs -> 8192 blocks.
// ---------------------------------------------------------------------------
__global__ __launch_bounds__(256) void rope_kernel(unsigned short* __restrict__ k,
                                                   const float* __restrict__ tab) {
  const int p = blockIdx.x * 256 + threadIdx.x;   // 0..2^21-1
  const int j = p & 31;
  const int s = (p >> 5) & (SEQ - 1);
  const int bh = p >> 16;
  const int b = bh >> 4;
  const f32x2 t = *(const f32x2*)&tab[(((size_t)(b * SEQ + s)) * 32 + j) * 2];
  const float cs = t[0], sn = t[1];
  unsigned int* wp = (unsigned int*)k + ((p >> 5) * 32 + j);
  const unsigned int u = *wp;
  const float e = bf2f((unsigned short)(u & 0xffffu));
  const float o = bf2f((unsigned short)(u >> 16));
  *wp = (unsigned int)f2bf(e * cs - o * sn) | ((unsigned int)f2bf(e * sn + o * cs) << 16);
}

// ---------------------------------------------------------------------------
// Flash attention (round-8 proven structure): 4 waves x 16 q-rows, 1024
// blocks, K+V double-buffer, swapped-operand MFMA, defer-max, XOR-swizzled
// Ps, LDS 40960 B. NEW: Q roped+scaled in-register at block start (lane's 8
// dims = 4 complete even/odd pairs; no cross-lane exchange).
// ---------------------------------------------------------------------------
#define MNEG -1e30f
#define QBLK 64
#define LOG2E 1.4426950408889634f

template<int BUF>
__device__ __forceinline__ void flash_tile(
    int kt, int nkv, int qt, int qbase, int wq, int c, int g, int tid,
    const unsigned short* (&kp)[2], const unsigned short* (&vp)[2],
    unsigned short (&Ks)[2][64 * 64], unsigned short (&Vs)[2][64 * 64],
    unsigned short (&Ps)[64 * 64],
    const bf16x8 (&qf)[2], f32x4 (&acco)[4], float& m_r, float& l_r) {
  const int kvb = kt * 64;
  // ---- prefetch next K/V tile into buffer BUF^1 (landed by end barrier) ----
  if (kt + 1 < nkv) {
#pragma unroll
    for (int i = 0; i < 2; ++i) {
      const int t8 = (tid + i * 256) * 8;
      __builtin_amdgcn_global_load_lds((gas_t)kp[i], (las_t)(Ks[BUF ^ 1] + t8), 16, 0, 0);
      __builtin_amdgcn_global_load_lds((gas_t)vp[i], (las_t)(Vs[BUF ^ 1] + t8), 16, 0, 0);
      kp[i] += 64 * HDIM;   // next K tile: +64 rows
      vp[i] += 64;          // next V^T tile: +64 cols
    }
  }

  // ---- S^T = K Q^T : D col = q (lane c), row = k_local (n*16 + g*4 + jj) ----
  f32x4 accs[4];
#pragma unroll
  for (int n = 0; n < 4; ++n)
#pragma unroll
    for (int j = 0; j < 4; ++j) accs[n][j] = 0.f;
  __builtin_amdgcn_s_setprio(1);
#pragma unroll
  for (int kk = 0; kk < 2; ++kk)
#pragma unroll
    for (int n = 0; n < 4; ++n) {
      const int r = n * 16 + c;
      const int sl = (kk * 4 + g) ^ (r & 7);
      const bf16x8 ak = *(const bf16x8*)&Ks[BUF][r * 64 + sl * 8];
      accs[n] = __builtin_amdgcn_mfma_f32_16x16x32_bf16(ak, qf[kk], accs[n], 0, 0, 0);
    }
  __builtin_amdgcn_s_setprio(0);

  // ---- causal mask (only on diagonal tile) ----
  const int qg = qbase + wq + c;
  if (kt == qt) {
#pragma unroll
    for (int n = 0; n < 4; ++n)
#pragma unroll
      for (int jj = 0; jj < 4; ++jj)
        if (kvb + n * 16 + g * 4 + jj > qg) accs[n][jj] = MNEG;
  }

  // ---- online softmax, one q-row per lane; defer-max rescale (THR=8) ----
  float rm = accs[0][0];
#pragma unroll
  for (int n = 0; n < 4; ++n)
#pragma unroll
    for (int jj = 0; jj < 4; ++jj) rm = fmaxf(rm, accs[n][jj]);
  rm = fmaxf(rm, __shfl_xor(rm, 16));
  rm = fmaxf(rm, __shfl_xor(rm, 32));
  if (!__all(rm <= m_r + 8.f)) {
    const float mn = fmaxf(m_r, rm);
    const float al = exp2f((m_r - mn) * LOG2E);
    l_r *= al;
#pragma unroll
    for (int n = 0; n < 4; ++n)
#pragma unroll
      for (int jj = 0; jj < 4; ++jj) acco[n][jj] *= al;
    m_r = mn;
  }
  float rs = 0.f;
#pragma unroll
  for (int n = 0; n < 4; ++n)
#pragma unroll
    for (int jj = 0; jj < 4; ++jj) {
      const float pv = exp2f((accs[n][jj] - m_r) * LOG2E);
      accs[n][jj] = pv;
      rs += pv;
    }
  rs += __shfl_xor(rs, 16);
  rs += __shfl_xor(rs, 32);
  l_r += rs;

  // ---- P^T -> LDS (XOR-swizzled [64][64]): 4 bf16 per n via 8B store ----
  const int pr = wq + c;
  const int px = (pr & 7) << 3;
#pragma unroll
  for (int n = 0; n < 4; ++n) {
    u16x4 pk4;
#pragma unroll
    for (int jj = 0; jj < 4; ++jj) pk4[jj] = f2bf(accs[n][jj]);
    *(u16x4*)&Ps[pr * 64 + ((n * 16 + g * 4) ^ px)] = pk4;
  }

  // ---- O^T += V^T P^T ----
  __builtin_amdgcn_s_setprio(1);
#pragma unroll
  for (int kk = 0; kk < 2; ++kk) {
    const bf16x8 pb = *(const bf16x8*)&Ps[pr * 64 + ((kk * 32 + g * 8) ^ px)];
#pragma unroll
    for (int n = 0; n < 4; ++n) {
      const int r = n * 16 + c;
      const int sl = (kk * 4 + g) ^ (r & 7);
      const bf16x8 av = *(const bf16x8*)&Vs[BUF][r * 64 + sl * 8];
      acco[n] = __builtin_amdgcn_mfma_f32_16x16x32_bf16(av, pb, acco[n], 0, 0, 0);
    }
  }
  __builtin_amdgcn_s_setprio(0);
  __syncthreads();  // drains prefetch vmcnt; publishes BUF^1; protects buffers
}

__global__ __launch_bounds__(256, 4) void flash_kernel(
    const unsigned short* __restrict__ q, const unsigned short* __restrict__ k,
    const unsigned short* __restrict__ vt, unsigned short* __restrict__ o,
    const float* __restrict__ tab) {
  __shared__ unsigned short Ks[2][64 * 64];   // 16 KB double-buffered
  __shared__ unsigned short Vs[2][64 * 64];   // 16 KB double-buffered
  __shared__ unsigned short Ps[64 * 64];      //  8 KB XOR-swizzled

  const int wg = blockIdx.x;                  // 0..1023, sorted big-first
  const int qt = (SEQ / QBLK - 1) - (wg >> 5);
  const int bh = wg & 31;
  const int qbase = qt * QBLK;
  const int tid = threadIdx.x, lane = tid & 63, w = tid >> 6;
  const int c = lane & 15, g = lane >> 4;
  const int wq = w * 16;
  const size_t tb = (size_t)bh * SEQ * HDIM;

  // ---- Q fragments: load raw, apply RoPE + 0.125 scale in-register ----
  // lane's 8 dims = d0..d0+7 with d0 = kk*32 + g*8: 4 complete (even,odd) pairs.
  const int srow0 = qbase + wq + c;
  const size_t rsb = (size_t)((bh >> 4) * SEQ + srow0) * 32;  // tab row base (pairs)
  bf16x8 qf[2];
#pragma unroll
  for (int kk = 0; kk < 2; ++kk) {
    const u16x8 qr = *(const u16x8*)(q + tb + (size_t)srow0 * HDIM + kk * 32 + g * 8);
    const int pd0 = kk * 16 + g * 4;
    const f32x4 t0 = *(const f32x4*)&tab[(rsb + pd0) * 2];      // {c0,s0,c1,s1}
    const f32x4 t1 = *(const f32x4*)&tab[(rsb + pd0) * 2 + 4];  // {c2,s2,c3,s3}
    u16x8 outp;
#pragma unroll
    for (int j = 0; j < 4; ++j) {
      const float cs = (j < 2) ? t0[2 * j] : t1[2 * (j - 2)];
      const float sn = (j < 2) ? t0[2 * j + 1] : t1[2 * (j - 2) + 1];
      const float e = bf2f(qr[2 * j]);
      const float od = bf2f(qr[2 * j + 1]);
      outp[2 * j]     = f2bf((e * cs - od * sn) * 0.125f);
      outp[2 * j + 1] = f2bf((e * sn + od * cs) * 0.125f);
    }
    qf[kk] = __builtin_bit_cast(bf16x8, outp);
  }

  // ---- persistent staging pointers (pre-swizzled source) ----
  const unsigned short* kp[2];
  const unsigned short* vp[2];
#pragma unroll
  for (int i = 0; i < 2; ++i) {
    const int t = tid + i * 256;
    const int r = t >> 3;
    const int sl = (t & 7) ^ (r & 7);
    kp[i] = k + tb + (size_t)r * HDIM + sl * 8;
    vp[i] = vt + tb + (size_t)r * SEQ + sl * 8;
  }
  // ---- stage tile 0 into buffer 0; advance pointers to tile 1 ----
#pragma unroll
  for (int i = 0; i < 2; ++i) {
    const int t8 = (tid + i * 256) * 8;
    __builtin_amdgcn_global_load_lds((gas_t)kp[i], (las_t)(Ks[0] + t8), 16, 0, 0);
    __builtin_amdgcn_global_load_lds((gas_t)vp[i], (las_t)(Vs[0] + t8), 16, 0, 0);
    kp[i] += 64 * HDIM;
    vp[i] += 64;
  }
  __syncthreads();

  f32x4 acco[4];
#pragma unroll
  for (int n = 0; n < 4; ++n)
#pragma unroll
    for (int j = 0; j < 4; ++j) acco[n][j] = 0.f;
  float m_r = MNEG, l_r = 0.f;

  const int nkv = qt + 1;
  int kt = 0;
  for (; kt + 2 <= nkv; kt += 2) {
    flash_tile<0>(kt,     nkv, qt, qbase, wq, c, g, tid, kp, vp, Ks, Vs, Ps, qf, acco, m_r, l_r);
    flash_tile<1>(kt + 1, nkv, qt, qbase, wq, c, g, tid, kp, vp, Ks, Vs, Ps, qf, acco, m_r, l_r);
  }
  if (kt < nkv)
    flash_tile<0>(kt, nkv, qt, qbase, wq, c, g, tid, kp, vp, Ks, Vs, Ps, qf, acco, m_r, l_r);

  // ---- epilogue: O/l, store [B,S,H*64]; lane c owns row qbase+wq+c ----
  const float rl = 1.f / fmaxf(l_r, 1e-20f);
  const int b = bh >> 4, h = bh & 15;
#pragma unroll
  for (int n = 0; n < 4; ++n) {
    u16x4 pk;
#pragma unroll
    for (int jj = 0; jj < 4; ++jj) pk[jj] = f2bf(acco[n][jj] * rl);
    *(u16x4*)&o[(size_t)(b * SEQ + srow0) * DMODEL + h * 64 + n * 16 + g * 4] = pk;
  }
}

// ---------------------------------------------------------------------------
extern "C" void kernel_launch(void* const* d_in, const int* in_sizes, int n_in,
                              void* d_out, int out_size, void* d_ws, size_t ws_size,
                              hipStream_t stream) {
  (void)in_sizes; (void)n_in; (void)out_size; (void)ws_size;
  const size_t MB = (size_t)1 << 20;
  char* ws = (char*)d_ws;
  unsigned short* xb  = (unsigned short*)(ws);            // 8 MB (reused as ow)
  unsigned short* Wqb = (unsigned short*)(ws + 8 * MB);   // 2 MB each
  unsigned short* Wkb = (unsigned short*)(ws + 10 * MB);
  unsigned short* Wvb = (unsigned short*)(ws + 12 * MB);
  unsigned short* Wob = (unsigned short*)(ws + 14 * MB);
  unsigned short* qw  = (unsigned short*)(ws + 16 * MB);  // 8 MB
  unsigned short* kw  = (unsigned short*)(ws + 24 * MB);  // 8 MB
  unsigned short* vtw = (unsigned short*)(ws + 32 * MB);  // 8 MB
  int* flags          = (int*)(ws + 40 * MB);
  float* tab          = (float*)(ws + 40 * MB + 4096);    // 1 MB cos/sin table
  unsigned short* ow  = xb;  // x dead after qkv_gemm

  const dim3 blk(256);
  probe_kernel<<<1, 64, 0, stream>>>((const unsigned int*)d_in[0], (const int*)d_in[5], flags);
  rope_table_kernel<<<512, blk, 0, stream>>>((const int*)d_in[5], flags, tab);
  conv_kernel<<<4096, blk, 0, stream>>>(d_in[0], d_in[1], d_in[2], d_in[3], d_in[4], xb, flags);
  qkv_gemm_kernel<<<dim3(32, 8, 3), blk, 0, stream>>>(xb, Wqb, Wkb, Wvb, qw, kw, vtw);
  rope_kernel<<<8192, blk, 0, stream>>>(kw, tab);
  flash_kernel<<<dim3(1024), blk, 0, stream>>>(qw, kw, vtw, ow, tab);
  out_gemm_kernel<<<dim3(64, 8), blk, 0, stream>>>(ow, Wob, d_out, flags);
}